// Round 1
// baseline (33429.196 us; speedup 1.0000x reference)
//
#include <hip/hip_runtime.h>
#include <math.h>
#include <stdint.h>

#define TT 672
#define NFREQ 337
#define DM 128
#define DFF 256
#define LENMAX 1344
#define CWTLEN 5376

struct FiltParams { int L[8]; int off[8]; int doff[8]; };

// ---------------- DFT: fl2d[b][f] = mean_n |X[b,f,n]| ----------------
__global__ void k_dft(const float* __restrict__ x, float* __restrict__ fl2d) {
  __shared__ float ct[TT], st[TT];
  __shared__ float red[128];
  int f = blockIdx.x, b = blockIdx.y, n = threadIdx.x;
  for (int k = n; k < TT; k += 128) {
    float th = (float)(6.283185307179586 * (double)k / 672.0);
    ct[k] = cosf(th); st[k] = sinf(th);
  }
  __syncthreads();
  float re = 0.f, im = 0.f;
  const float* xb = x + ((size_t)b * TT) * DM + n;
  int k = 0;
  for (int t = 0; t < TT; ++t) {
    float xv = xb[(size_t)t * DM];
    re += xv * ct[k]; im += xv * st[k];
    k += f; if (k >= TT) k -= TT;
  }
  red[n] = sqrtf(re * re + im * im);
  __syncthreads();
  for (int s = 64; s > 0; s >>= 1) { if (n < s) red[n] += red[n + s]; __syncthreads(); }
  if (n == 0) fl2d[b * NFREQ + f] = red[0] * (1.f / 128.f);
}

// ---------------- control: top-2, periods, softmax weights, bias means ----------------
__global__ void k_ctrl(const float* __restrict__ fl2d,
                       const float* __restrict__ b1, const float* __restrict__ b2,
                       int* __restrict__ ctrl, float* __restrict__ wsm,
                       float* __restrict__ b1e, float* __restrict__ b2e) {
  __shared__ float fl[NFREQ];
  int tid = threadIdx.x;
  for (int f = tid; f < NFREQ; f += 256) {
    float s = 0.f;
    for (int b = 0; b < 8; ++b) s += fl2d[b * NFREQ + f];
    fl[f] = s * 0.125f;
  }
  __syncthreads();
  if (tid == 0) {
    fl[0] = 0.f;
    int t1 = 1; float v1 = fl[1];
    for (int f = 2; f < NFREQ; ++f) if (fl[f] > v1) { v1 = fl[f]; t1 = f; }
    int t2 = (t1 == 1) ? 2 : 1; float v2 = fl[t2];
    for (int f = t2 + 1; f < NFREQ; ++f) { if (f == t1) continue; if (fl[f] > v2) { v2 = fl[f]; t2 = f; } }
    int tops[2] = { t1, t2 };
    for (int kk = 0; kk < 2; ++kk) {
      int p = TT / tops[kk];
      int H = (TT + p - 1) / p;
      ctrl[kk * 3 + 0] = p; ctrl[kk * 3 + 1] = H; ctrl[kk * 3 + 2] = H * p;
    }
    ctrl[6] = TT; ctrl[7] = 8; ctrl[8] = CWTLEN;
    ctrl[9] = t1; ctrl[10] = t2;
    for (int b = 0; b < 8; ++b) {
      float p0 = fl2d[b * NFREQ + t1], p1 = fl2d[b * NFREQ + t2];
      float m = fmaxf(p0, p1);
      float e0 = expf(p0 - m), e1 = expf(p1 - m);
      float inv = 1.f / (e0 + e1);
      wsm[b * 2 + 0] = e0 * inv; wsm[b * 2 + 1] = e1 * inv;
    }
  }
  if (tid < 256) { float s = 0.f; for (int i = 0; i < 6; ++i) s += b1[i * DFF + tid]; b1e[tid] = s * (1.f / 6.f); }
  if (tid < 128) { float s = 0.f; for (int i = 0; i < 6; ++i) s += b2[i * DM + tid]; b2e[tid] = s * (1.f / 6.f); }
}

// ---------------- effective weights: weff[ci][u*11+v][co] = mean_i masked ----------------
__global__ void k_wprep(const float* __restrict__ W, float* __restrict__ weff,
                        int Cout, int Cin) {
  int co = blockIdx.x, ci = blockIdx.y, t = threadIdx.x;
  if (t >= 121) return;
  int u = t / 11, v = t - u * 11;
  int du = u - 5; if (du < 0) du = -du;
  int dv = v - 5; if (dv < 0) dv = -dv;
  int m = du > dv ? du : dv;
  size_t kstride = (size_t)Cout * Cin * 121;
  size_t base = ((size_t)co * Cin + ci) * 121 + t;
  float s = 0.f;
  for (int i = m; i < 6; ++i) s += W[i * kstride + base];
  weff[((size_t)ci * 121 + t) * Cout + co] = s * (1.f / 6.f);
}

// ---------------- int_psi (matches numpy float64 cumsum) ----------------
__global__ void k_psi(float* __restrict__ ipsi) {
  __shared__ double ps[1024];
  int tid = threadIdx.x;
  for (int i = tid; i < 1024; i += 256) {
    double xv = -8.0 + (double)i * (16.0 / 1023.0);
    ps[i] = exp(-xv * xv * 0.5) * cos(5.0 * xv);
  }
  __syncthreads();
  if (tid == 0) {
    double acc = 0.0;
    for (int i = 0; i < 1024; ++i) { acc += ps[i]; ps[i] = acc * (16.0 / 1023.0); }
  }
  __syncthreads();
  for (int i = tid; i < 1024; i += 256) ipsi[i] = (float)ps[i];
}

// ---------------- FIR filters d_s[k] = -sqrt(s)*(f[k-1]-f[k]), k in [0,L] ----------------
__global__ void k_filt(const float* __restrict__ ipsi, float* __restrict__ d, FiltParams fp) {
  __shared__ float ip[1024];
  int si = blockIdx.x, tid = threadIdx.x;
  for (int i = tid; i < 1024; i += 256) ip[i] = ipsi[i];
  __syncthreads();
  double texp = (si == 7) ? 8.0 : (-1.0 + (double)si * (9.0 / 7.0));
  double s = pow(2.0, texp);
  double sstep = s * (16.0 / 1023.0);
  double sq = sqrt(s);
  int L = fp.L[si];
  float* dd = d + fp.doff[si];
  for (int k = tid; k <= L; k += 256) {
    float fk = 0.f, fkm = 0.f;
    if (k < L) { int j = (int)((double)k / sstep); if (j > 1023) j = 1023; fk = ip[j]; }
    if (k > 0) { int j = (int)((double)(k - 1) / sstep); if (j > 1023) j = 1023; fkm = ip[j]; }
    dd[k] = (float)(-sq * (double)(fkm - fk));
  }
}

// ---------------- CWT: coef[b][n][si*672+tau] ----------------
__global__ __launch_bounds__(256) void k_cwt(const float* __restrict__ x, const float* __restrict__ d,
                      float* __restrict__ coef, FiltParams fp) {
  __shared__ float dl[4130];
  __shared__ float tb[128 * 33];
  int tile = blockIdx.x, si = blockIdx.y, b = blockIdx.z;
  int tid = threadIdx.x;
  int n = tid & 127, g = tid >> 7;
  int L = fp.L[si], off = fp.off[si];
  for (int i = tid; i < L + 33; i += 256) {
    int k = i - 16;
    dl[i] = ((unsigned)k <= (unsigned)L) ? d[fp.doff[si] + k] : 0.f;
  }
  __syncthreads();
  int ta = tile * 32 + g * 16;
  float acc[16];
  #pragma unroll
  for (int j = 0; j < 16; ++j) acc[j] = 0.f;
  int rlo = ta + off - L + 1; if (rlo < 0) rlo = 0;
  int rhi = ta + off + 17; if (rhi > TT) rhi = TT;
  const float* xb = x + ((size_t)b * TT) * DM + n;
  for (int r = rlo; r < rhi; ++r) {
    float xv = xb[(size_t)r * DM];
    int kb16 = 16 + r - ta - off + L - 1;
    #pragma unroll
    for (int j = 0; j < 16; ++j) acc[j] += dl[kb16 - j] * xv;
  }
  #pragma unroll
  for (int j = 0; j < 16; ++j) tb[n * 33 + g * 16 + j] = acc[j];
  __syncthreads();
  int n2 = tid >> 1, half = tid & 1;
  float* op = coef + ((size_t)(b * DM + n2)) * CWTLEN + si * TT + tile * 32 + half * 16;
  const float* tp = tb + n2 * 33 + half * 16;
  #pragma unroll
  for (int j = 0; j < 16; ++j) op[j] = tp[j];
}

// ---------------- transpose x -> xT[b][n][t] ----------------
__global__ void k_xT(const float* __restrict__ x, float* __restrict__ xT) {
  __shared__ float tile[32][33];
  int t0 = blockIdx.x * 32, n0 = blockIdx.y * 32, b = blockIdx.z;
  int tx = threadIdx.x & 31, ty = threadIdx.x >> 5;
  for (int i = ty; i < 32; i += 8)
    tile[i][tx] = x[((size_t)b * TT + t0 + i) * DM + n0 + tx];
  __syncthreads();
  for (int i = ty; i < 32; i += 8)
    xT[((size_t)b * DM + n0 + i) * TT + t0 + tx] = tile[tx][i];
}

// ---------------- generic period/image conv, 11x11 SAME, fused bias(+GELU) ----------------
__global__ __launch_bounds__(256) void k_conv(
    const float* __restrict__ in, const float* __restrict__ wgt,
    const float* __restrict__ bias, float* __restrict__ out,
    const int* __restrict__ ctrl, int slot,
    int Cin, int Cout,
    int inStrideC, int inStrideT, int inBatchStride,
    int inLenStatic, int useDynLen,
    int outStride, int outBatchStride, int outLenCap, int doGelu)
{
  __shared__ float smem[64 * 33];
  int p = ctrl[slot * 3 + 0], len = ctrl[slot * 3 + 2];
  int inLen = useDynLen ? len : inLenStatic;
  int lenCap = len < outLenCap ? len : outLenCap;
  int t0 = blockIdx.x * 32;
  if (t0 >= lenCap) return;
  int b = blockIdx.y;
  int co0 = blockIdx.z * 64;
  int tid = threadIdx.x;
  int lane = tid & 63, pg = tid >> 6;
  int co = co0 + lane;
  const float* inb = in + (size_t)b * inBatchStride;

  float acc[8];
  #pragma unroll
  for (int j = 0; j < 8; ++j) acc[j] = 0.f;

  int w0 = t0 % p;
  bool fast = (w0 >= 5) && (w0 <= p - 37);
  unsigned mrow[8];
  if (!fast) {
    #pragma unroll
    for (int j = 0; j < 8; ++j) {
      int t = t0 + pg * 8 + j;
      int w = t % p;
      int vlo = 5 - w; if (vlo < 0) vlo = 0;
      int vhi = p + 4 - w; if (vhi > 10) vhi = 10;
      mrow[j] = (vhi >= vlo) ? (((1u << (vhi - vlo + 1)) - 1u) << vlo) : 0u;
    }
  }

  for (int cc = 0; cc < Cin; cc += 8) {
    for (int u = 0; u < 11; ++u) {
      __syncthreads();
      int tpBase = t0 - 5 + (u - 5) * p;
      for (int idx = tid; idx < 8 * 42; idx += 256) {
        int c = idx / 42, jj = idx - c * 42;
        int tp = tpBase + jj;
        float v = 0.f;
        if ((unsigned)tp < (unsigned)inLen)
          v = inb[(size_t)(cc + c) * inStrideC + (size_t)tp * inStrideT];
        smem[c * 48 + jj] = v;
      }
      __syncthreads();
      for (int c = 0; c < 8; ++c) {
        float r[18];
        #pragma unroll
        for (int i = 0; i < 18; ++i) r[i] = smem[c * 48 + pg * 8 + i];
        const float* wrow = wgt + ((size_t)(cc + c) * 121 + (size_t)u * 11) * Cout + co;
        if (fast) {
          #pragma unroll
          for (int v = 0; v < 11; ++v) {
            float wv = wrow[(size_t)v * Cout];
            #pragma unroll
            for (int j = 0; j < 8; ++j) acc[j] = fmaf(r[j + v], wv, acc[j]);
          }
        } else {
          #pragma unroll
          for (int v = 0; v < 11; ++v) {
            float wv = wrow[(size_t)v * Cout];
            #pragma unroll
            for (int j = 0; j < 8; ++j) {
              float val = ((mrow[j] >> v) & 1u) ? r[j + v] : 0.f;
              acc[j] = fmaf(val, wv, acc[j]);
            }
          }
        }
      }
    }
  }

  float bv = bias[co];
  #pragma unroll
  for (int j = 0; j < 8; ++j) {
    float v = acc[j] + bv;
    if (doGelu) v = 0.5f * v * (1.f + erff(v * 0.7071067811865476f));
    acc[j] = v;
  }
  __syncthreads();
  #pragma unroll
  for (int j = 0; j < 8; ++j) smem[lane * 33 + pg * 8 + j] = acc[j];
  __syncthreads();
  int oc = tid >> 2, part = tid & 3;
  int tt0 = t0 + part * 8;
  float* op = out + (size_t)b * outBatchStride + (size_t)(co0 + oc) * outStride;
  const float* tp2 = smem + oc * 33 + part * 8;
  #pragma unroll
  for (int jj = 0; jj < 8; ++jj) {
    int t = tt0 + jj;
    if (t < lenCap) op[t] = tp2[jj];
  }
}

// ---------------- final combine ----------------
__global__ void k_combine(const float* __restrict__ x, const float* __restrict__ wrp,
    const float* __restrict__ bo0, const float* __restrict__ bo1,
    const float* __restrict__ Wsc, const float* __restrict__ bsc,
    const float* __restrict__ wsm, float* __restrict__ out) {
  int b = blockIdx.y;
  int t = blockIdx.x * 224 + threadIdx.x;
  if (threadIdx.x >= 224) return;
  float s0 = wsm[b * 2 + 0], s1 = wsm[b * 2 + 1];
  for (int n = 0; n < DM; ++n) {
    const float* wr = wrp + ((size_t)(b * DM + n)) * CWTLEN + t;
    float accv = bsc[n];
    #pragma unroll
    for (int s = 0; s < 8; ++s) accv += wr[(size_t)s * TT] * Wsc[n * 8 + s];
    size_t bo_i = ((size_t)(b * DM + n)) * LENMAX + t;
    float po = s0 * bo0[bo_i] + s1 * bo1[bo_i];
    size_t xi = ((size_t)b * TT + t) * DM + n;
    out[xi] = 0.6513215599f * accv + 0.3486784401f * po + x[xi];
  }
}

extern "C" void kernel_launch(void* const* d_in, const int* in_sizes, int n_in,
                              void* d_out, int out_size, void* d_ws, size_t ws_size,
                              hipStream_t stream) {
  const float* x   = (const float*)d_in[0];
  const float* W1  = (const float*)d_in[1];
  const float* b1  = (const float*)d_in[2];
  const float* W2  = (const float*)d_in[3];
  const float* b2  = (const float*)d_in[4];
  const float* Wsc = (const float*)d_in[5];
  const float* bsc = (const float*)d_in[6];
  float* out = (float*)d_out;

  float* ws = (float*)d_ws;
  size_t o = 0;
  int*   ctrl = (int*)ws;           o += 32;
  float* wsm  = ws + o;             o += 16;
  float* b1e  = ws + o;             o += 256;
  float* b2e  = ws + o;             o += 128;
  float* fl2d = ws + o;             o += (size_t)8 * NFREQ;
  float* ipsi = ws + o;             o += 1024;
  float* filt = ws + o;             o += 8192;
  float* w1e  = ws + o;             o += (size_t)128 * 121 * 256;
  float* w2e  = ws + o;             o += (size_t)256 * 121 * 128;
  float* coef = ws + o;             o += (size_t)8 * DM * CWTLEN;   // also wr_pre
  float* h1   = ws + o;             o += (size_t)8 * DFF * CWTLEN;  // also branch h1
  float* bo0  = ws + o;             o += (size_t)8 * DM * LENMAX;
  float* bo1  = ws + o;             o += (size_t)8 * DM * LENMAX;
  float* xT   = ws + o;             o += (size_t)8 * DM * TT;

  FiltParams fp;
  {
    double step = 16.0 / 1023.0;
    int doff = 0;
    for (int i = 0; i < 8; ++i) {
      double t = (i == 7) ? 8.0 : (-1.0 + (double)i * (9.0 / 7.0));
      double s = pow(2.0, t);
      double stop = s * 16.0 + 1.0;
      int nmax = (int)ceil(stop);
      double sstep = s * step;
      int L = 0;
      for (int k = 0; k < nmax; ++k) {
        long j = (long)((double)k / sstep);
        if (j < 1024) L++; else break;
      }
      fp.L[i] = L;
      fp.off[i] = (L - 2) / 2;
      fp.doff[i] = doff;
      doff += L + 1;
    }
  }

  k_dft<<<dim3(NFREQ, 8), 128, 0, stream>>>(x, fl2d);
  k_ctrl<<<1, 256, 0, stream>>>(fl2d, b1, b2, ctrl, wsm, b1e, b2e);
  k_wprep<<<dim3(256, 128), 128, 0, stream>>>(W1, w1e, 256, 128);
  k_wprep<<<dim3(128, 256), 128, 0, stream>>>(W2, w2e, 128, 256);
  k_psi<<<1, 256, 0, stream>>>(ipsi);
  k_filt<<<8, 256, 0, stream>>>(ipsi, filt, fp);
  k_cwt<<<dim3(21, 8, 8), 256, 0, stream>>>(x, filt, coef, fp);
  k_xT<<<dim3(21, 4, 8), 256, 0, stream>>>(x, xT);

  // CWT conv1: coef -> h1 (gelu)
  k_conv<<<dim3(168, 8, 4), 256, 0, stream>>>(coef, w1e, b1e, h1, ctrl, 2,
      128, 256, CWTLEN, 1, DM * CWTLEN, CWTLEN, 0, CWTLEN, DFF * CWTLEN, 1 << 28, 1);
  // CWT conv2: h1 -> coef (wr_pre)
  k_conv<<<dim3(168, 8, 2), 256, 0, stream>>>(h1, w2e, b2e, coef, ctrl, 2,
      256, 128, CWTLEN, 1, DFF * CWTLEN, CWTLEN, 0, CWTLEN, DM * CWTLEN, 1 << 28, 0);
  // branch 0
  k_conv<<<dim3(42, 8, 4), 256, 0, stream>>>(xT, w1e, b1e, h1, ctrl, 0,
      128, 256, TT, 1, DM * TT, TT, 0, LENMAX, DFF * LENMAX, 1 << 28, 1);
  k_conv<<<dim3(21, 8, 2), 256, 0, stream>>>(h1, w2e, b2e, bo0, ctrl, 0,
      256, 128, LENMAX, 1, DFF * LENMAX, 0, 1, LENMAX, DM * LENMAX, TT, 0);
  // branch 1
  k_conv<<<dim3(42, 8, 4), 256, 0, stream>>>(xT, w1e, b1e, h1, ctrl, 1,
      128, 256, TT, 1, DM * TT, TT, 0, LENMAX, DFF * LENMAX, 1 << 28, 1);
  k_conv<<<dim3(21, 8, 2), 256, 0, stream>>>(h1, w2e, b2e, bo1, ctrl, 1,
      256, 128, LENMAX, 1, DFF * LENMAX, 0, 1, LENMAX, DM * LENMAX, TT, 0);

  k_combine<<<dim3(3, 8), 256, 0, stream>>>(x, coef, bo0, bo1, Wsc, bsc, wsm, out);
}

// Round 2
// 2613.343 us; speedup vs baseline: 12.7917x; 12.7917x over previous
//
#include <hip/hip_runtime.h>
#include <math.h>
#include <stdint.h>

#define TT 672
#define NFREQ 337
#define DM 128
#define DFF 256
#define QP_CWT 5456   // 8 * (672+10)
#define QPB 4096      // branch padded-row allocation stride
#define BN 256

typedef float f32x4 __attribute__((ext_vector_type(4)));
typedef short short8 __attribute__((ext_vector_type(8)));

struct FiltParams { int L[8]; int off[8]; int doff[8]; };

__device__ inline unsigned short f2b(float f) {
  unsigned u = __float_as_uint(f);
  return (unsigned short)((u + 0x7FFFu + ((u >> 16) & 1u)) >> 16);
}
__device__ inline float b2f(unsigned short s) {
  return __uint_as_float(((unsigned)s) << 16);
}

// ---------------- DFT: fl2d[b][f] = mean_n |X[b,f,n]| ----------------
__global__ void k_dft(const float* __restrict__ x, float* __restrict__ fl2d) {
  __shared__ float ct[TT], st[TT];
  __shared__ float red[128];
  int f = blockIdx.x, b = blockIdx.y, n = threadIdx.x;
  for (int k = n; k < TT; k += 128) {
    float th = (float)(6.283185307179586 * (double)k / 672.0);
    ct[k] = cosf(th); st[k] = sinf(th);
  }
  __syncthreads();
  float re = 0.f, im = 0.f;
  const float* xb = x + ((size_t)b * TT) * DM + n;
  int k = 0;
  for (int t = 0; t < TT; ++t) {
    float xv = xb[(size_t)t * DM];
    re += xv * ct[k]; im += xv * st[k];
    k += f; if (k >= TT) k -= TT;
  }
  red[n] = sqrtf(re * re + im * im);
  __syncthreads();
  for (int s = 64; s > 0; s >>= 1) { if (n < s) red[n] += red[n + s]; __syncthreads(); }
  if (n == 0) fl2d[b * NFREQ + f] = red[0] * (1.f / 128.f);
}

// ---------------- control: top-2, periods, softmax weights, bias means ----------------
__global__ void k_ctrl(const float* __restrict__ fl2d,
                       const float* __restrict__ b1, const float* __restrict__ b2,
                       int* __restrict__ ctrl, float* __restrict__ wsm,
                       float* __restrict__ b1e, float* __restrict__ b2e) {
  __shared__ float fl[NFREQ];
  int tid = threadIdx.x;
  for (int f = tid; f < NFREQ; f += 256) {
    float s = 0.f;
    for (int b = 0; b < 8; ++b) s += fl2d[b * NFREQ + f];
    fl[f] = s * 0.125f;
  }
  __syncthreads();
  if (tid == 0) {
    fl[0] = 0.f;
    int t1 = 1; float v1 = fl[1];
    for (int f = 2; f < NFREQ; ++f) if (fl[f] > v1) { v1 = fl[f]; t1 = f; }
    int t2 = (t1 == 1) ? 2 : 1; float v2 = fl[t2];
    for (int f = t2 + 1; f < NFREQ; ++f) { if (f == t1) continue; if (fl[f] > v2) { v2 = fl[f]; t2 = f; } }
    int tops[2] = { t1, t2 };
    for (int kk = 0; kk < 2; ++kk) {
      int p = TT / tops[kk];
      int H = (TT + p - 1) / p;
      ctrl[kk * 3 + 0] = p; ctrl[kk * 3 + 1] = H; ctrl[kk * 3 + 2] = H * (p + 10);
    }
    ctrl[6] = TT; ctrl[7] = 8; ctrl[8] = QP_CWT;
    ctrl[9] = t1; ctrl[10] = t2;
    for (int b = 0; b < 8; ++b) {
      float p0 = fl2d[b * NFREQ + t1], p1 = fl2d[b * NFREQ + t2];
      float m = fmaxf(p0, p1);
      float e0 = expf(p0 - m), e1 = expf(p1 - m);
      float inv = 1.f / (e0 + e1);
      wsm[b * 2 + 0] = e0 * inv; wsm[b * 2 + 1] = e1 * inv;
    }
  }
  if (tid < 256) { float s = 0.f; for (int i = 0; i < 6; ++i) s += b1[i * DFF + tid]; b1e[tid] = s * (1.f / 6.f); }
  if (tid < 128) { float s = 0.f; for (int i = 0; i < 6; ++i) s += b2[i * DM + tid]; b2e[tid] = s * (1.f / 6.f); }
}

// ---------------- effective weights -> bf16, layout wl[(uv)*Cout+co][ci] ----------------
__global__ void k_wprep(const float* __restrict__ W, unsigned short* __restrict__ wl,
                        int Cout, int Cin) {
  int co = blockIdx.x, ci = blockIdx.y, t = threadIdx.x;
  if (t >= 121) return;
  int u = t / 11, v = t - u * 11;
  int du = u - 5; if (du < 0) du = -du;
  int dv = v - 5; if (dv < 0) dv = -dv;
  int m = du > dv ? du : dv;
  size_t kstride = (size_t)Cout * Cin * 121;
  size_t base = ((size_t)co * Cin + ci) * 121 + t;
  float s = 0.f;
  for (int i = m; i < 6; ++i) s += W[i * kstride + base];
  wl[((size_t)t * Cout + co) * Cin + ci] = f2b(s * (1.f / 6.f));
}

// ---------------- int_psi (matches numpy float64 cumsum) ----------------
__global__ void k_psi(float* __restrict__ ipsi) {
  __shared__ double ps[1024];
  int tid = threadIdx.x;
  for (int i = tid; i < 1024; i += 256) {
    double xv = -8.0 + (double)i * (16.0 / 1023.0);
    ps[i] = exp(-xv * xv * 0.5) * cos(5.0 * xv);
  }
  __syncthreads();
  if (tid == 0) {
    double acc = 0.0;
    for (int i = 0; i < 1024; ++i) { acc += ps[i]; ps[i] = acc * (16.0 / 1023.0); }
  }
  __syncthreads();
  for (int i = tid; i < 1024; i += 256) ipsi[i] = (float)ps[i];
}

// ---------------- FIR filters ----------------
__global__ void k_filt(const float* __restrict__ ipsi, float* __restrict__ d, FiltParams fp) {
  __shared__ float ip[1024];
  int si = blockIdx.x, tid = threadIdx.x;
  for (int i = tid; i < 1024; i += 256) ip[i] = ipsi[i];
  __syncthreads();
  double texp = (si == 7) ? 8.0 : (-1.0 + (double)si * (9.0 / 7.0));
  double s = pow(2.0, texp);
  double sstep = s * (16.0 / 1023.0);
  double sq = sqrt(s);
  int L = fp.L[si];
  float* dd = d + fp.doff[si];
  for (int k = tid; k <= L; k += 256) {
    float fk = 0.f, fkm = 0.f;
    if (k < L) { int j = (int)((double)k / sstep); if (j > 1023) j = 1023; fk = ip[j]; }
    if (k > 0) { int j = (int)((double)(k - 1) / sstep); if (j > 1023) j = 1023; fkm = ip[j]; }
    dd[k] = (float)(-sq * (double)(fkm - fk));
  }
}

// ---------------- CWT -> padded bf16 image coef_pad[b][q][n] ----------------
__global__ __launch_bounds__(256) void k_cwt(const float* __restrict__ x, const float* __restrict__ d,
                      unsigned short* __restrict__ coef, FiltParams fp) {
  __shared__ float dl[4130];
  int tile = blockIdx.x, si = blockIdx.y, b = blockIdx.z;
  int tid = threadIdx.x;
  int n = tid & 127, g = tid >> 7;
  int L = fp.L[si], off = fp.off[si];
  for (int i = tid; i < L + 33; i += 256) {
    int k = i - 16;
    dl[i] = ((unsigned)k <= (unsigned)L) ? d[fp.doff[si] + k] : 0.f;
  }
  __syncthreads();
  int ta = tile * 32 + g * 16;
  float acc[16];
  #pragma unroll
  for (int j = 0; j < 16; ++j) acc[j] = 0.f;
  int rlo = ta + off - L + 1; if (rlo < 0) rlo = 0;
  int rhi = ta + off + 17; if (rhi > TT) rhi = TT;
  const float* xb = x + ((size_t)b * TT) * DM + n;
  for (int r = rlo; r < rhi; ++r) {
    float xv = xb[(size_t)r * DM];
    int kb16 = 16 + r - ta - off + L - 1;
    #pragma unroll
    for (int j = 0; j < 16; ++j) acc[j] += dl[kb16 - j] * xv;
  }
  unsigned short* op = coef + ((size_t)b * QP_CWT + (size_t)si * 682 + 5 + ta) * DM + n;
  #pragma unroll
  for (int j = 0; j < 16; ++j) op[(size_t)j * DM] = f2b(acc[j]);
}

// ---------------- zero the horizontal pad rows of coef_pad ----------------
__global__ void k_cwtpad(unsigned short* __restrict__ coef) {
  int b = blockIdx.x, si = blockIdx.y, n = threadIdx.x;
  for (int r = 0; r < 10; ++r) {
    int q = si * 682 + (r < 5 ? r : 672 + r);
    coef[((size_t)b * QP_CWT + q) * DM + n] = 0;
  }
}

// ---------------- build branch padded inputs xb_pad[slot][b][q][n] ----------------
__global__ void k_xpad(const float* __restrict__ x, const int* __restrict__ ctrl,
                       unsigned short* __restrict__ xb0, unsigned short* __restrict__ xb1) {
  int q = blockIdx.x, b = blockIdx.y, n = threadIdx.x;
  for (int slot = 0; slot < 2; ++slot) {
    int p = ctrl[slot * 3], QP = ctrl[slot * 3 + 2];
    if (q >= QP) continue;
    int p10 = p + 10;
    int row = q / p10, w = q - row * p10;
    float val = 0.f;
    if (w >= 5 && w < p + 5) {
      int t = row * p + (w - 5);
      if (t < TT) val = x[((size_t)b * TT + t) * DM + n];
    }
    unsigned short* dst = slot == 0 ? xb0 : xb1;
    dst[((size_t)b * QPB + q) * DM + n] = f2b(val);
  }
}

// ---------------- MFMA implicit-GEMM conv: out[b][q][co] = conv(in[b][q][ci]) ----------------
__global__ __launch_bounds__(512) void k_convm(
    const unsigned short* __restrict__ in, const unsigned short* __restrict__ wl,
    const float* __restrict__ bias, unsigned short* __restrict__ out,
    const int* __restrict__ ctrl, int slot, int Cin, int Cout,
    int inQS, int outQS, int doGelu)
{
  __shared__ unsigned short Alds[128 * 72];
  __shared__ unsigned short Blds[266 * 72];
  int p = ctrl[slot * 3], QP = ctrl[slot * 3 + 2];
  int p10 = p + 10;
  int q0 = blockIdx.x * BN;
  if (q0 >= QP) return;
  int b = blockIdx.y, cob = blockIdx.z * 128;
  int tid = threadIdx.x;
  int wave = tid >> 6, lane = tid & 63;
  int wr = wave >> 2, wc = wave & 3;
  int lrow = lane & 15, lhi = lane >> 4;

  f32x4 acc[4][4];
  #pragma unroll
  for (int i = 0; i < 4; ++i)
    #pragma unroll
    for (int j = 0; j < 4; ++j)
      #pragma unroll
      for (int r = 0; r < 4; ++r) acc[i][j][r] = 0.f;

  const unsigned short* inb = in + (size_t)b * inQS * Cin;

  for (int cc = 0; cc < Cin; cc += 64) {
    for (int u = 0; u < 11; ++u) {
      int qb0 = q0 - 5 + (u - 5) * p10;
      if (qb0 >= QP || qb0 + 266 <= 0) continue;  // block-uniform
      __syncthreads();
      // stage B segment [266][64ci] (zero outside [0,QP))
      for (int idx = tid; idx < 266 * 8; idx += 512) {
        int row = idx >> 3, part = idx & 7;
        int qs = qb0 + row;
        short8 vv = {0,0,0,0,0,0,0,0};
        if ((unsigned)qs < (unsigned)QP)
          vv = *(const short8*)&inb[(size_t)qs * Cin + cc + part * 8];
        *(short8*)&Blds[row * 72 + part * 8] = vv;
      }
      // stage A for v=0
      {
        size_t wb = ((size_t)(u * 11) * Cout + cob);
        for (int idx = tid; idx < 1024; idx += 512) {
          int row = idx >> 3, part = idx & 7;
          *(short8*)&Alds[row * 72 + part * 8] =
              *(const short8*)&wl[(wb + row) * Cin + cc + part * 8];
        }
      }
      __syncthreads();
      for (int v = 0; v < 11; ++v) {
        // T14: issue next-v weight loads before the MFMA cluster
        short8 pf0, pf1;
        int r0 = tid >> 3, p0i = tid & 7;
        int r1 = (tid + 512) >> 3, p1i = tid & 7;
        if (v < 10) {
          size_t wb = ((size_t)(u * 11 + v + 1) * Cout + cob);
          pf0 = *(const short8*)&wl[(wb + r0) * Cin + cc + p0i * 8];
          pf1 = *(const short8*)&wl[(wb + r1) * Cin + cc + p1i * 8];
        }
        #pragma unroll
        for (int ks = 0; ks < 2; ++ks) {
          short8 af[4], bf[4];
          #pragma unroll
          for (int mi = 0; mi < 4; ++mi)
            af[mi] = *(short8*)&Alds[(wr * 64 + mi * 16 + lrow) * 72 + ks * 32 + lhi * 8];
          #pragma unroll
          for (int ni = 0; ni < 4; ++ni)
            bf[ni] = *(short8*)&Blds[(wc * 64 + ni * 16 + lrow + v) * 72 + ks * 32 + lhi * 8];
          #pragma unroll
          for (int mi = 0; mi < 4; ++mi)
            #pragma unroll
            for (int ni = 0; ni < 4; ++ni)
              acc[mi][ni] = __builtin_amdgcn_mfma_f32_16x16x32_bf16(af[mi], bf[ni], acc[mi][ni], 0, 0, 0);
        }
        __syncthreads();
        if (v < 10) {
          *(short8*)&Alds[r0 * 72 + p0i * 8] = pf0;
          *(short8*)&Alds[r1 * 72 + p1i * 8] = pf1;
        }
        __syncthreads();
      }
    }
  }

  // epilogue: bias (+gelu), zero pad columns, pack bf16, store [q][co]
  #pragma unroll
  for (int mi = 0; mi < 4; ++mi) {
    int cb2 = cob + wr * 64 + mi * 16 + lhi * 4;
    float bv0 = bias[cb2], bv1 = bias[cb2 + 1], bv2 = bias[cb2 + 2], bv3 = bias[cb2 + 3];
    #pragma unroll
    for (int ni = 0; ni < 4; ++ni) {
      int q = q0 + wc * 64 + ni * 16 + lrow;
      if (q >= QP) continue;
      int w = q % p10;
      bool pad = (w < 5) || (w >= p + 5);
      float v0 = acc[mi][ni][0] + bv0;
      float v1 = acc[mi][ni][1] + bv1;
      float v2 = acc[mi][ni][2] + bv2;
      float v3 = acc[mi][ni][3] + bv3;
      if (doGelu) {
        v0 = 0.5f * v0 * (1.f + erff(v0 * 0.7071067811865476f));
        v1 = 0.5f * v1 * (1.f + erff(v1 * 0.7071067811865476f));
        v2 = 0.5f * v2 * (1.f + erff(v2 * 0.7071067811865476f));
        v3 = 0.5f * v3 * (1.f + erff(v3 * 0.7071067811865476f));
      }
      if (pad) { v0 = 0.f; v1 = 0.f; v2 = 0.f; v3 = 0.f; }
      uint2 pk;
      pk.x = (unsigned)f2b(v0) | ((unsigned)f2b(v1) << 16);
      pk.y = (unsigned)f2b(v2) | ((unsigned)f2b(v3) << 16);
      *(uint2*)&out[((size_t)b * outQS + q) * Cout + cb2] = pk;
    }
  }
}

// ---------------- final combine ----------------
__global__ void k_combine(const float* __restrict__ x, const unsigned short* __restrict__ wrp,
    const unsigned short* __restrict__ bo0, const unsigned short* __restrict__ bo1,
    const float* __restrict__ Wsc, const float* __restrict__ bsc,
    const float* __restrict__ wsm, const int* __restrict__ ctrl, float* __restrict__ out) {
  int t = blockIdx.x, b = blockIdx.y, n = threadIdx.x;
  float accv = bsc[n];
  #pragma unroll
  for (int s = 0; s < 8; ++s)
    accv += b2f(wrp[((size_t)b * QP_CWT + (size_t)s * 682 + 5 + t) * DM + n]) * Wsc[n * 8 + s];
  int p0 = ctrl[0], p1 = ctrl[3];
  int q0 = (t / p0) * (p0 + 10) + 5 + (t % p0);
  int q1 = (t / p1) * (p1 + 10) + 5 + (t % p1);
  float po = wsm[b * 2 + 0] * b2f(bo0[((size_t)b * QPB + q0) * DM + n])
           + wsm[b * 2 + 1] * b2f(bo1[((size_t)b * QPB + q1) * DM + n]);
  size_t xi = ((size_t)b * TT + t) * DM + n;
  out[xi] = 0.6513215599f * accv + 0.3486784401f * po + x[xi];
}

extern "C" void kernel_launch(void* const* d_in, const int* in_sizes, int n_in,
                              void* d_out, int out_size, void* d_ws, size_t ws_size,
                              hipStream_t stream) {
  const float* x   = (const float*)d_in[0];
  const float* W1  = (const float*)d_in[1];
  const float* b1  = (const float*)d_in[2];
  const float* W2  = (const float*)d_in[3];
  const float* b2  = (const float*)d_in[4];
  const float* Wsc = (const float*)d_in[5];
  const float* bsc = (const float*)d_in[6];
  float* out = (float*)d_out;

  char* base = (char*)d_ws;
  size_t off = 0;
  auto alloc = [&](size_t bytes) -> void* {
    void* pp = base + off; off = (off + bytes + 255) & ~(size_t)255; return pp;
  };
  int*   ctrl = (int*)  alloc(32 * 4);
  float* wsm  = (float*)alloc(16 * 4);
  float* b1e  = (float*)alloc(256 * 4);
  float* b2e  = (float*)alloc(128 * 4);
  float* fl2d = (float*)alloc((size_t)8 * NFREQ * 4);
  float* ipsi = (float*)alloc(1024 * 4);
  float* filt = (float*)alloc(8192 * 4);
  unsigned short* wl1  = (unsigned short*)alloc((size_t)121 * 256 * 128 * 2);
  unsigned short* wl2  = (unsigned short*)alloc((size_t)121 * 256 * 128 * 2);
  unsigned short* coefp= (unsigned short*)alloc((size_t)8 * QP_CWT * DM * 2);
  unsigned short* h1p  = (unsigned short*)alloc((size_t)8 * QP_CWT * DFF * 2);
  unsigned short* wrp  = (unsigned short*)alloc((size_t)8 * QP_CWT * DM * 2);
  unsigned short* xb0  = (unsigned short*)alloc((size_t)8 * QPB * DM * 2);
  unsigned short* xb1  = (unsigned short*)alloc((size_t)8 * QPB * DM * 2);
  unsigned short* bo0  = (unsigned short*)alloc((size_t)8 * QPB * DM * 2);
  unsigned short* bo1  = (unsigned short*)alloc((size_t)8 * QPB * DM * 2);

  FiltParams fp;
  {
    double step = 16.0 / 1023.0;
    int doff = 0;
    for (int i = 0; i < 8; ++i) {
      double t = (i == 7) ? 8.0 : (-1.0 + (double)i * (9.0 / 7.0));
      double s = pow(2.0, t);
      double stop = s * 16.0 + 1.0;
      int nmax = (int)ceil(stop);
      double sstep = s * step;
      int L = 0;
      for (int k = 0; k < nmax; ++k) {
        long j = (long)((double)k / sstep);
        if (j < 1024) L++; else break;
      }
      fp.L[i] = L;
      fp.off[i] = (L - 2) / 2;
      fp.doff[i] = doff;
      doff += L + 1;
    }
  }

  k_dft<<<dim3(NFREQ, 8), 128, 0, stream>>>(x, fl2d);
  k_ctrl<<<1, 256, 0, stream>>>(fl2d, b1, b2, ctrl, wsm, b1e, b2e);
  k_wprep<<<dim3(256, 128), 128, 0, stream>>>(W1, wl1, 256, 128);
  k_wprep<<<dim3(128, 256), 128, 0, stream>>>(W2, wl2, 128, 256);
  k_psi<<<1, 256, 0, stream>>>(ipsi);
  k_filt<<<8, 256, 0, stream>>>(ipsi, filt, fp);
  k_cwt<<<dim3(21, 8, 8), 256, 0, stream>>>(x, filt, coefp, fp);
  k_cwtpad<<<dim3(8, 8), 128, 0, stream>>>(coefp);
  k_xpad<<<dim3(QPB, 8), 128, 0, stream>>>(x, ctrl, xb0, xb1);

  // CWT branch: conv1 (gelu) then conv2
  k_convm<<<dim3(22, 8, 2), 512, 0, stream>>>(coefp, wl1, b1e, h1p, ctrl, 2, 128, 256, QP_CWT, QP_CWT, 1);
  k_convm<<<dim3(22, 8, 1), 512, 0, stream>>>(h1p, wl2, b2e, wrp, ctrl, 2, 256, 128, QP_CWT, QP_CWT, 0);
  // period branch 0
  k_convm<<<dim3(16, 8, 2), 512, 0, stream>>>(xb0, wl1, b1e, h1p, ctrl, 0, 128, 256, QPB, QP_CWT, 1);
  k_convm<<<dim3(16, 8, 1), 512, 0, stream>>>(h1p, wl2, b2e, bo0, ctrl, 0, 256, 128, QP_CWT, QPB, 0);
  // period branch 1
  k_convm<<<dim3(16, 8, 2), 512, 0, stream>>>(xb1, wl1, b1e, h1p, ctrl, 1, 128, 256, QPB, QP_CWT, 1);
  k_convm<<<dim3(16, 8, 1), 512, 0, stream>>>(h1p, wl2, b2e, bo1, ctrl, 1, 256, 128, QP_CWT, QPB, 0);

  k_combine<<<dim3(TT, 8), 128, 0, stream>>>(x, wrp, bo0, bo1, Wsc, bsc, wsm, ctrl, out);
}

// Round 3
// 1806.342 us; speedup vs baseline: 18.5066x; 1.4468x over previous
//
#include <hip/hip_runtime.h>
#include <math.h>
#include <stdint.h>

#define TT 672
#define NFREQ 337
#define DM 128
#define DFF 256
#define QP_CWT 5456   // 8 * (672+10)
#define QPB 4096      // branch padded-row allocation stride
#define BN 256

typedef float f32x4 __attribute__((ext_vector_type(4)));
typedef short short8 __attribute__((ext_vector_type(8)));

struct FiltParams { int L[8]; int off[8]; int doff[8]; };

__device__ inline unsigned short f2b(float f) {
  unsigned u = __float_as_uint(f);
  return (unsigned short)((u + 0x7FFFu + ((u >> 16) & 1u)) >> 16);
}
__device__ inline float b2f(unsigned short s) {
  return __uint_as_float(((unsigned)s) << 16);
}

__device__ inline void gld16(const void* g, void* l) {
  __builtin_amdgcn_global_load_lds(
      (const __attribute__((address_space(1))) unsigned int*)g,
      (__attribute__((address_space(3))) unsigned int*)l, 16, 0, 0);
}

// ---------------- DFT: fl2d[b][f] = mean_n |X[b,f,n]| ----------------
__global__ void k_dft(const float* __restrict__ x, float* __restrict__ fl2d) {
  __shared__ float ct[TT], st[TT];
  __shared__ float red[128];
  int f = blockIdx.x, b = blockIdx.y, n = threadIdx.x;
  for (int k = n; k < TT; k += 128) {
    float th = (float)(6.283185307179586 * (double)k / 672.0);
    ct[k] = cosf(th); st[k] = sinf(th);
  }
  __syncthreads();
  float re = 0.f, im = 0.f;
  const float* xb = x + ((size_t)b * TT) * DM + n;
  int k = 0;
  for (int t = 0; t < TT; ++t) {
    float xv = xb[(size_t)t * DM];
    re += xv * ct[k]; im += xv * st[k];
    k += f; if (k >= TT) k -= TT;
  }
  red[n] = sqrtf(re * re + im * im);
  __syncthreads();
  for (int s = 64; s > 0; s >>= 1) { if (n < s) red[n] += red[n + s]; __syncthreads(); }
  if (n == 0) fl2d[b * NFREQ + f] = red[0] * (1.f / 128.f);
}

// ---------------- control ----------------
__global__ void k_ctrl(const float* __restrict__ fl2d,
                       const float* __restrict__ b1, const float* __restrict__ b2,
                       int* __restrict__ ctrl, float* __restrict__ wsm,
                       float* __restrict__ b1e, float* __restrict__ b2e) {
  __shared__ float fl[NFREQ];
  int tid = threadIdx.x;
  for (int f = tid; f < NFREQ; f += 256) {
    float s = 0.f;
    for (int b = 0; b < 8; ++b) s += fl2d[b * NFREQ + f];
    fl[f] = s * 0.125f;
  }
  __syncthreads();
  if (tid == 0) {
    fl[0] = 0.f;
    int t1 = 1; float v1 = fl[1];
    for (int f = 2; f < NFREQ; ++f) if (fl[f] > v1) { v1 = fl[f]; t1 = f; }
    int t2 = (t1 == 1) ? 2 : 1; float v2 = fl[t2];
    for (int f = t2 + 1; f < NFREQ; ++f) { if (f == t1) continue; if (fl[f] > v2) { v2 = fl[f]; t2 = f; } }
    int tops[2] = { t1, t2 };
    for (int kk = 0; kk < 2; ++kk) {
      int p = TT / tops[kk];
      int H = (TT + p - 1) / p;
      ctrl[kk * 3 + 0] = p; ctrl[kk * 3 + 1] = H; ctrl[kk * 3 + 2] = H * (p + 10);
    }
    ctrl[6] = 672; ctrl[7] = 8; ctrl[8] = QP_CWT;
    for (int b = 0; b < 8; ++b) {
      float p0 = fl2d[b * NFREQ + t1], p1 = fl2d[b * NFREQ + t2];
      float m = fmaxf(p0, p1);
      float e0 = expf(p0 - m), e1 = expf(p1 - m);
      float inv = 1.f / (e0 + e1);
      wsm[b * 2 + 0] = e0 * inv; wsm[b * 2 + 1] = e1 * inv;
    }
  }
  if (tid < 256) { float s = 0.f; for (int i = 0; i < 6; ++i) s += b1[i * DFF + tid]; b1e[tid] = s * (1.f / 6.f); }
  if (tid < 128) { float s = 0.f; for (int i = 0; i < 6; ++i) s += b2[i * DM + tid]; b2e[tid] = s * (1.f / 6.f); }
}

// ---------------- effective weights -> bf16, pre-swizzled slab layout ----------------
// wl[((uv*(Cout/128)+cot)*(Cin/64)+c64)][row=co&127][64 shorts, unit-swizzled]
__global__ void k_wprep(const float* __restrict__ W, unsigned short* __restrict__ wl,
                        int Cout, int Cin) {
  int co = blockIdx.x, ci = blockIdx.y, t = threadIdx.x;
  if (t >= 121) return;
  int u = t / 11, v = t - u * 11;
  int du = u - 5; if (du < 0) du = -du;
  int dv = v - 5; if (dv < 0) dv = -dv;
  int m = du > dv ? du : dv;
  size_t kstride = (size_t)Cout * Cin * 121;
  size_t base = ((size_t)co * Cin + ci) * 121 + t;
  float s = 0.f;
  for (int i = m; i < 6; ++i) s += W[i * kstride + base];
  int cot = co >> 7, row = co & 127;
  int c64 = ci >> 6, part = (ci >> 3) & 7, within = ci & 7;
  int nc = Cin >> 6;
  size_t slab = ((size_t)t * (Cout >> 7) + cot) * nc + c64;
  wl[slab * 8192 + row * 64 + (((part ^ (row & 7)) << 3) + within)] = f2b(s * (1.f / 6.f));
}

// ---------------- int_psi ----------------
__global__ void k_psi(float* __restrict__ ipsi) {
  __shared__ double ps[1024];
  int tid = threadIdx.x;
  for (int i = tid; i < 1024; i += 256) {
    double xv = -8.0 + (double)i * (16.0 / 1023.0);
    ps[i] = exp(-xv * xv * 0.5) * cos(5.0 * xv);
  }
  __syncthreads();
  if (tid == 0) {
    double acc = 0.0;
    for (int i = 0; i < 1024; ++i) { acc += ps[i]; ps[i] = acc * (16.0 / 1023.0); }
  }
  __syncthreads();
  for (int i = tid; i < 1024; i += 256) ipsi[i] = (float)ps[i];
}

// ---------------- FIR filters ----------------
__global__ void k_filt(const float* __restrict__ ipsi, float* __restrict__ d, FiltParams fp) {
  __shared__ float ip[1024];
  int si = blockIdx.x, tid = threadIdx.x;
  for (int i = tid; i < 1024; i += 256) ip[i] = ipsi[i];
  __syncthreads();
  double texp = (si == 7) ? 8.0 : (-1.0 + (double)si * (9.0 / 7.0));
  double s = pow(2.0, texp);
  double sstep = s * (16.0 / 1023.0);
  double sq = sqrt(s);
  int L = fp.L[si];
  float* dd = d + fp.doff[si];
  for (int k = tid; k <= L; k += 256) {
    float fk = 0.f, fkm = 0.f;
    if (k < L) { int j = (int)((double)k / sstep); if (j > 1023) j = 1023; fk = ip[j]; }
    if (k > 0) { int j = (int)((double)(k - 1) / sstep); if (j > 1023) j = 1023; fkm = ip[j]; }
    dd[k] = (float)(-sq * (double)(fkm - fk));
  }
}

// ---------------- CWT -> padded bf16 image coef_pad[b][q][n] ----------------
__global__ __launch_bounds__(256) void k_cwt(const float* __restrict__ x, const float* __restrict__ d,
                      unsigned short* __restrict__ coef, FiltParams fp) {
  __shared__ float dl[4130];
  int tile = blockIdx.x, si = blockIdx.y, b = blockIdx.z;
  int tid = threadIdx.x;
  int n = tid & 127, g = tid >> 7;
  int L = fp.L[si], off = fp.off[si];
  for (int i = tid; i < L + 33; i += 256) {
    int k = i - 16;
    dl[i] = ((unsigned)k <= (unsigned)L) ? d[fp.doff[si] + k] : 0.f;
  }
  __syncthreads();
  int ta = tile * 32 + g * 16;
  float acc[16];
  #pragma unroll
  for (int j = 0; j < 16; ++j) acc[j] = 0.f;
  int rlo = ta + off - L + 1; if (rlo < 0) rlo = 0;
  int rhi = ta + off + 17; if (rhi > TT) rhi = TT;
  const float* xb = x + ((size_t)b * TT) * DM + n;
  for (int r = rlo; r < rhi; ++r) {
    float xv = xb[(size_t)r * DM];
    int kb16 = 16 + r - ta - off + L - 1;
    #pragma unroll
    for (int j = 0; j < 16; ++j) acc[j] += dl[kb16 - j] * xv;
  }
  unsigned short* op = coef + ((size_t)b * QP_CWT + (size_t)si * 682 + 5 + ta) * DM + n;
  #pragma unroll
  for (int j = 0; j < 16; ++j) op[(size_t)j * DM] = f2b(acc[j]);
}

// ---------------- zero pad rows of coef_pad ----------------
__global__ void k_cwtpad(unsigned short* __restrict__ coef) {
  int b = blockIdx.x, si = blockIdx.y, n = threadIdx.x;
  for (int r = 0; r < 10; ++r) {
    int q = si * 682 + (r < 5 ? r : 672 + r);
    coef[((size_t)b * QP_CWT + q) * DM + n] = 0;
  }
}

// ---------------- build branch padded inputs ----------------
__global__ void k_xpad(const float* __restrict__ x, const int* __restrict__ ctrl,
                       unsigned short* __restrict__ xb0, unsigned short* __restrict__ xb1) {
  int q = blockIdx.x, b = blockIdx.y, n = threadIdx.x;
  for (int slot = 0; slot < 2; ++slot) {
    int p = ctrl[slot * 3], QP = ctrl[slot * 3 + 2];
    if (q >= QP) continue;
    int p10 = p + 10;
    int row = q / p10, w = q - row * p10;
    float val = 0.f;
    if (w >= 5 && w < p + 5) {
      int t = row * p + (w - 5);
      if (t < TT) val = x[((size_t)b * TT + t) * DM + n];
    }
    unsigned short* dst = slot == 0 ? xb0 : xb1;
    dst[((size_t)b * QPB + q) * DM + n] = f2b(val);
  }
}

// ---------------- merged MFMA implicit-GEMM conv ----------------
// blockIdx.x: 0..21 CWT tile, 22..37 branch0 tile, 38..53 branch1 tile
// block computes 128co x 256q; 4 waves, each 128co x 64q (acc 8x4 frags)
__global__ __launch_bounds__(256, 2) void k_convm(
    const unsigned short* __restrict__ inC, const unsigned short* __restrict__ in0,
    const unsigned short* __restrict__ in1, const unsigned short* __restrict__ wl,
    const float* __restrict__ bias,
    unsigned short* __restrict__ outC, unsigned short* __restrict__ out0,
    unsigned short* __restrict__ out1,
    const int* __restrict__ ctrl, int Cin, int Cout,
    int QSC, int QSB, int doGelu)
{
  __shared__ __align__(16) unsigned short Alds[2][128 * 64];
  __shared__ __align__(16) unsigned short Blds[266 * 64];

  int xt = blockIdx.x;
  int job, tile;
  if (xt < 22) { job = 2; tile = xt; }
  else if (xt < 38) { job = 0; tile = xt - 22; }
  else { job = 1; tile = xt - 38; }
  int p, QP;
  if (job == 2) { p = 672; QP = QP_CWT; }
  else { p = ctrl[job * 3]; QP = ctrl[job * 3 + 2]; }
  int p10 = p + 10;
  int q0 = tile * BN;
  if (q0 >= QP) return;

  const unsigned short* in = job == 2 ? inC : (job == 0 ? in0 : in1);
  unsigned short* outp = job == 2 ? outC : (job == 0 ? out0 : out1);
  int QS = job == 2 ? QSC : QSB;

  int b = blockIdx.y, cot = blockIdx.z;
  int tid = threadIdx.x;
  int wv = tid >> 6, lane = tid & 63, lrow = lane & 15, lhi = lane >> 4;
  int nc = Cin >> 6, ncot = Cout >> 7;

  f32x4 acc[8][4];
  #pragma unroll
  for (int i = 0; i < 8; ++i)
    #pragma unroll
    for (int j = 0; j < 4; ++j)
      #pragma unroll
      for (int r = 0; r < 4; ++r) acc[i][j][r] = 0.f;

  const unsigned short* inb = in + (size_t)b * QS * Cin;

  for (int c64 = 0; c64 < nc; ++c64) {
    for (int u = 0; u < 11; ++u) {
      int qb0 = q0 - 5 + (u - 5) * p10;
      if (qb0 >= QP || qb0 + 266 <= 0) continue;
      __syncthreads();
      // stage B (reg -> LDS, unit-swizzled rows of 128B)
      for (int idx = tid; idx < 266 * 8; idx += 256) {
        int row = idx >> 3, part = idx & 7;
        int qs = qb0 + row;
        short8 vv = {0, 0, 0, 0, 0, 0, 0, 0};
        if ((unsigned)qs < (unsigned)QP)
          vv = *(const short8*)&inb[(size_t)qs * Cin + c64 * 64 + part * 8];
        *(short8*)&Blds[row * 64 + ((part ^ (row & 7)) << 3)] = vv;
      }
      // stage A[v=0] (linear 16KB copy, already swizzled in global)
      {
        const unsigned short* asrc = wl + ((size_t)((u * 11) * ncot + cot) * nc + c64) * 8192;
        #pragma unroll
        for (int i = 0; i < 4; ++i) {
          int off = (wv * 4 + i) * 1024;
          gld16((const char*)asrc + off + lane * 16, (char*)&Alds[0][0] + off);
        }
      }
      __syncthreads();
      for (int v = 0; v < 11; ++v) {
        const unsigned short* Acur = &Alds[v & 1][0];
        // prefetch A[v+1] into the other buffer
        if (v < 10) {
          const unsigned short* asrc = wl + ((size_t)((u * 11 + v + 1) * ncot + cot) * nc + c64) * 8192;
          char* Anxt = (char*)&Alds[(v + 1) & 1][0];
          #pragma unroll
          for (int i = 0; i < 4; ++i) {
            int off = (wv * 4 + i) * 1024;
            gld16((const char*)asrc + off + lane * 16, Anxt + off);
          }
        }
        #pragma unroll
        for (int ks = 0; ks < 2; ++ks) {
          short8 af[8], bf[4];
          #pragma unroll
          for (int mi = 0; mi < 8; ++mi) {
            int row = mi * 16 + lrow;
            af[mi] = *(const short8*)&Acur[row * 64 + (((ks * 4 + lhi) ^ (row & 7)) << 3)];
          }
          #pragma unroll
          for (int ni = 0; ni < 4; ++ni) {
            int row = wv * 64 + ni * 16 + lrow + v;
            bf[ni] = *(const short8*)&Blds[row * 64 + (((ks * 4 + lhi) ^ (row & 7)) << 3)];
          }
          #pragma unroll
          for (int mi = 0; mi < 8; ++mi)
            #pragma unroll
            for (int ni = 0; ni < 4; ++ni)
              acc[mi][ni] = __builtin_amdgcn_mfma_f32_16x16x32_bf16(af[mi], bf[ni], acc[mi][ni], 0, 0, 0);
        }
        __syncthreads();
      }
    }
  }

  // epilogue
  int qv[4]; bool pad[4];
  #pragma unroll
  for (int ni = 0; ni < 4; ++ni) {
    int q = q0 + wv * 64 + ni * 16 + lrow;
    qv[ni] = q;
    int w = q - (q / p10) * p10;
    pad[ni] = (w < 5) || (w >= p + 5);
  }
  #pragma unroll
  for (int mi = 0; mi < 8; ++mi) {
    int co = cot * 128 + mi * 16 + lhi * 4;
    float bv0 = bias[co], bv1 = bias[co + 1], bv2 = bias[co + 2], bv3 = bias[co + 3];
    #pragma unroll
    for (int ni = 0; ni < 4; ++ni) {
      int q = qv[ni];
      if (q >= QP) continue;
      float v0 = acc[mi][ni][0] + bv0;
      float v1 = acc[mi][ni][1] + bv1;
      float v2 = acc[mi][ni][2] + bv2;
      float v3 = acc[mi][ni][3] + bv3;
      if (doGelu) {
        v0 = 0.5f * v0 * (1.f + erff(v0 * 0.7071067811865476f));
        v1 = 0.5f * v1 * (1.f + erff(v1 * 0.7071067811865476f));
        v2 = 0.5f * v2 * (1.f + erff(v2 * 0.7071067811865476f));
        v3 = 0.5f * v3 * (1.f + erff(v3 * 0.7071067811865476f));
      }
      if (pad[ni]) { v0 = 0.f; v1 = 0.f; v2 = 0.f; v3 = 0.f; }
      uint2 pk;
      pk.x = (unsigned)f2b(v0) | ((unsigned)f2b(v1) << 16);
      pk.y = (unsigned)f2b(v2) | ((unsigned)f2b(v3) << 16);
      *(uint2*)&outp[((size_t)b * QS + q) * Cout + co] = pk;
    }
  }
}

// ---------------- final combine ----------------
__global__ void k_combine(const float* __restrict__ x, const unsigned short* __restrict__ wrp,
    const unsigned short* __restrict__ bo0, const unsigned short* __restrict__ bo1,
    const float* __restrict__ Wsc, const float* __restrict__ bsc,
    const float* __restrict__ wsm, const int* __restrict__ ctrl, float* __restrict__ out) {
  int t = blockIdx.x, b = blockIdx.y, n = threadIdx.x;
  float accv = bsc[n];
  #pragma unroll
  for (int s = 0; s < 8; ++s)
    accv += b2f(wrp[((size_t)b * QP_CWT + (size_t)s * 682 + 5 + t) * DM + n]) * Wsc[n * 8 + s];
  int p0 = ctrl[0], p1 = ctrl[3];
  int q0 = (t / p0) * (p0 + 10) + 5 + (t % p0);
  int q1 = (t / p1) * (p1 + 10) + 5 + (t % p1);
  float po = wsm[b * 2 + 0] * b2f(bo0[((size_t)b * QPB + q0) * DM + n])
           + wsm[b * 2 + 1] * b2f(bo1[((size_t)b * QPB + q1) * DM + n]);
  size_t xi = ((size_t)b * TT + t) * DM + n;
  out[xi] = 0.6513215599f * accv + 0.3486784401f * po + x[xi];
}

extern "C" void kernel_launch(void* const* d_in, const int* in_sizes, int n_in,
                              void* d_out, int out_size, void* d_ws, size_t ws_size,
                              hipStream_t stream) {
  const float* x   = (const float*)d_in[0];
  const float* W1  = (const float*)d_in[1];
  const float* b1  = (const float*)d_in[2];
  const float* W2  = (const float*)d_in[3];
  const float* b2  = (const float*)d_in[4];
  const float* Wsc = (const float*)d_in[5];
  const float* bsc = (const float*)d_in[6];
  float* out = (float*)d_out;

  char* base = (char*)d_ws;
  size_t off = 0;
  auto alloc = [&](size_t bytes) -> void* {
    void* pp = base + off; off = (off + bytes + 255) & ~(size_t)255; return pp;
  };
  int*   ctrl = (int*)  alloc(32 * 4);
  float* wsm  = (float*)alloc(16 * 4);
  float* b1e  = (float*)alloc(256 * 4);
  float* b2e  = (float*)alloc(128 * 4);
  float* fl2d = (float*)alloc((size_t)8 * NFREQ * 4);
  float* ipsi = (float*)alloc(1024 * 4);
  float* filt = (float*)alloc(8192 * 4);
  unsigned short* wl1  = (unsigned short*)alloc((size_t)121 * 2 * 2 * 8192 * 2);
  unsigned short* wl2  = (unsigned short*)alloc((size_t)121 * 1 * 4 * 8192 * 2);
  unsigned short* coefp= (unsigned short*)alloc((size_t)8 * QP_CWT * DM * 2);
  unsigned short* h1p  = (unsigned short*)alloc((size_t)8 * QP_CWT * DFF * 2);
  unsigned short* h1b0 = (unsigned short*)alloc((size_t)8 * QPB * DFF * 2);
  unsigned short* h1b1 = (unsigned short*)alloc((size_t)8 * QPB * DFF * 2);
  unsigned short* wrp  = (unsigned short*)alloc((size_t)8 * QP_CWT * DM * 2);
  unsigned short* xb0  = (unsigned short*)alloc((size_t)8 * QPB * DM * 2);
  unsigned short* xb1  = (unsigned short*)alloc((size_t)8 * QPB * DM * 2);
  unsigned short* bo0  = (unsigned short*)alloc((size_t)8 * QPB * DM * 2);
  unsigned short* bo1  = (unsigned short*)alloc((size_t)8 * QPB * DM * 2);

  FiltParams fp;
  {
    double step = 16.0 / 1023.0;
    int doff = 0;
    for (int i = 0; i < 8; ++i) {
      double t = (i == 7) ? 8.0 : (-1.0 + (double)i * (9.0 / 7.0));
      double s = pow(2.0, t);
      double stop = s * 16.0 + 1.0;
      int nmax = (int)ceil(stop);
      double sstep = s * step;
      int L = 0;
      for (int k = 0; k < nmax; ++k) {
        long j = (long)((double)k / sstep);
        if (j < 1024) L++; else break;
      }
      fp.L[i] = L;
      fp.off[i] = (L - 2) / 2;
      fp.doff[i] = doff;
      doff += L + 1;
    }
  }

  k_dft<<<dim3(NFREQ, 8), 128, 0, stream>>>(x, fl2d);
  k_ctrl<<<1, 256, 0, stream>>>(fl2d, b1, b2, ctrl, wsm, b1e, b2e);
  k_wprep<<<dim3(256, 128), 128, 0, stream>>>(W1, wl1, 256, 128);
  k_wprep<<<dim3(128, 256), 128, 0, stream>>>(W2, wl2, 128, 256);
  k_psi<<<1, 256, 0, stream>>>(ipsi);
  k_filt<<<8, 256, 0, stream>>>(ipsi, filt, fp);
  k_cwt<<<dim3(21, 8, 8), 256, 0, stream>>>(x, filt, coefp, fp);
  k_cwtpad<<<dim3(8, 8), 128, 0, stream>>>(coefp);
  k_xpad<<<dim3(QPB, 8), 128, 0, stream>>>(x, ctrl, xb0, xb1);

  // merged conv1 (gelu): inputs {coefp, xb0, xb1} -> {h1p, h1b0, h1b1}
  k_convm<<<dim3(54, 8, 2), 256, 0, stream>>>(coefp, xb0, xb1, wl1, b1e,
      h1p, h1b0, h1b1, ctrl, 128, 256, QP_CWT, QPB, 1);
  // merged conv2: inputs {h1p, h1b0, h1b1} -> {wrp, bo0, bo1}
  k_convm<<<dim3(54, 8, 1), 256, 0, stream>>>(h1p, h1b0, h1b1, wl2, b2e,
      wrp, bo0, bo1, ctrl, 256, 128, QP_CWT, QPB, 0);

  k_combine<<<dim3(TT, 8), 128, 0, stream>>>(x, wrp, bo0, bo1, Wsc, bsc, wsm, ctrl, out);
}